// Round 1
// baseline (228.610 us; speedup 1.0000x reference)
//
#include <hip/hip_runtime.h>

// MHSA: B=2, T=4096, D=512, H=8, HD=64.
// Needs 42 MB workspace.

typedef __attribute__((ext_vector_type(8))) short bf16x8;
typedef __attribute__((ext_vector_type(4))) float f32x4;

#define DEV static __device__ __forceinline__

DEV unsigned short f2bf(float f) {
    union { float f; unsigned u; } a; a.f = f;
    unsigned r = a.u + 0x7FFFu + ((a.u >> 16) & 1u);   // RNE
    return (unsigned short)(r >> 16);
}

DEV void glds16(const void* g, void* l) {
    __builtin_amdgcn_global_load_lds(
        (const __attribute__((address_space(1))) void*)g,
        (__attribute__((address_space(3))) void*)l,
        16, 0, 0);
}

DEV f32x4 mfma(bf16x8 a, bf16x8 b, f32x4 c) {
    return __builtin_amdgcn_mfma_f32_16x16x32_bf16(a, b, c, 0, 0, 0);
}

// ---------------- cast x -> bf16 ----------------
__global__ __launch_bounds__(256) void k_cast(const float* __restrict__ x,
                                              unsigned short* __restrict__ xb, int n4) {
    for (int i = blockIdx.x * 256 + threadIdx.x; i < n4; i += gridDim.x * 256) {
        float4 v = ((const float4*)x)[i];
        ushort4 o;
        o.x = f2bf(v.x); o.y = f2bf(v.y); o.z = f2bf(v.z); o.w = f2bf(v.w);
        ((ushort4*)xb)[i] = o;
    }
}

// ---------------- transpose + cast weight: src f32 [R][C] -> dst bf16 [C][R] ----------------
__global__ __launch_bounds__(256) void k_tcast(const float* __restrict__ src,
                                               unsigned short* __restrict__ dst,
                                               int R, int C) {
    __shared__ float t[64][65];
    const int bx = blockIdx.x, by = blockIdx.y, tid = threadIdx.x;
#pragma unroll
    for (int e = 0; e < 16; ++e) {
        int idx = e * 256 + tid;
        int r = idx >> 6, c = idx & 63;
        t[r][c] = src[(by * 64 + r) * C + bx * 64 + c];
    }
    __syncthreads();
#pragma unroll
    for (int e = 0; e < 16; ++e) {
        int idx = e * 256 + tid;
        int r = idx >> 6, c = idx & 63;
        dst[(bx * 64 + r) * R + by * 64 + c] = f2bf(t[c][r]);
    }
}

// ---------------- GEMM1: qkv = xb[8192x512] @ wT[1536x512]^T + b ----------------
// writes Q,K as [b][h][t][64] bf16 (Q pre-scaled by 0.125*log2e), V transposed [b][h][64][t]
__global__ __launch_bounds__(256) void k_gemm_qkv(
    const unsigned short* __restrict__ xb, const unsigned short* __restrict__ wT,
    const float* __restrict__ bias,
    unsigned short* __restrict__ Qb, unsigned short* __restrict__ Kb,
    unsigned short* __restrict__ Vtb)
{
    __shared__ __attribute__((aligned(16))) unsigned short lA[128 * 64];
    __shared__ __attribute__((aligned(16))) unsigned short lB[128 * 64];
    const int tid = threadIdx.x, lane = tid & 63, w = tid >> 6;
    const int qi = lane & 15, g = lane >> 4;
    const int bm = blockIdx.x & 63, bn = blockIdx.x >> 6;
    const int m0 = bm * 128, n0 = bn * 128;
    const int wr = w >> 1, wc = w & 1;
    const int srow = lane >> 3, sch = (lane & 7) ^ srow;
    const int swz = (qi & 7) << 4;
    f32x4 zero = {0.f, 0.f, 0.f, 0.f};
    f32x4 acc[4][4];
#pragma unroll
    for (int i = 0; i < 4; ++i)
#pragma unroll
        for (int j = 0; j < 4; ++j) acc[i][j] = zero;

    for (int kt = 0; kt < 8; ++kt) {
#pragma unroll
        for (int i = 0; i < 4; ++i) {
            int c = w * 4 + i;
            int row = c * 8 + srow;
            glds16(xb + (m0 + row) * 512 + kt * 64 + sch * 8, (char*)lA + c * 1024);
            glds16(wT + (n0 + row) * 512 + kt * 64 + sch * 8, (char*)lB + c * 1024);
        }
        __syncthreads();
#pragma unroll
        for (int k2 = 0; k2 < 2; ++k2) {
            bf16x8 af[4], bfr[4];
#pragma unroll
            for (int i = 0; i < 4; ++i) {
                int ra = wr * 64 + i * 16 + qi;
                af[i] = *(const bf16x8*)((const char*)lA + ra * 128 + ((k2 * 64 + g * 16) ^ swz));
                int rb = wc * 64 + i * 16 + qi;
                bfr[i] = *(const bf16x8*)((const char*)lB + rb * 128 + ((k2 * 64 + g * 16) ^ swz));
            }
#pragma unroll
            for (int mi = 0; mi < 4; ++mi)
#pragma unroll
                for (int ni = 0; ni < 4; ++ni)
                    acc[mi][ni] = mfma(af[mi], bfr[ni], acc[mi][ni]);
        }
        __syncthreads();
    }

    const int comp = n0 >> 9;  // 0=q 1=k 2=v (whole 128-col tile is one component)
#pragma unroll
    for (int mi = 0; mi < 4; ++mi) {
        int mbase = m0 + wr * 64 + mi * 16 + g * 4;
        int b = mbase >> 12, t = mbase & 4095;
#pragma unroll
        for (int ni = 0; ni < 4; ++ni) {
            int n = n0 + wc * 64 + ni * 16 + qi;
            float bn = bias[n];
            int nn = n & 511;
            int h = nn >> 6, d = nn & 63;
            if (comp == 0) {
                unsigned short* dst = Qb + ((b * 8 + h) * 4096 + t) * 64 + d;
#pragma unroll
                for (int r = 0; r < 4; ++r)
                    dst[r * 64] = f2bf((acc[mi][ni][r] + bn) * 0.18033688011112042f);
            } else if (comp == 1) {
                unsigned short* dst = Kb + ((b * 8 + h) * 4096 + t) * 64 + d;
#pragma unroll
                for (int r = 0; r < 4; ++r)
                    dst[r * 64] = f2bf(acc[mi][ni][r] + bn);
            } else {
                ushort4 pk4;
                pk4.x = f2bf(acc[mi][ni][0] + bn);
                pk4.y = f2bf(acc[mi][ni][1] + bn);
                pk4.z = f2bf(acc[mi][ni][2] + bn);
                pk4.w = f2bf(acc[mi][ni][3] + bn);
                *(ushort4*)(Vtb + ((b * 8 + h) * 64 + d) * 4096 + t) = pk4;
            }
        }
    }
}

// ---------------- flash attention (causal), 1 block = (b,h, 64 q-rows), 4 waves x 16 rows ----------------
__global__ __launch_bounds__(256) void k_attn(
    const unsigned short* __restrict__ Qb, const unsigned short* __restrict__ Kb,
    const unsigned short* __restrict__ Vtb, unsigned short* __restrict__ Ob)
{
    __shared__ __attribute__((aligned(16))) unsigned short lK[64 * 64];
    __shared__ __attribute__((aligned(16))) unsigned short lV[64 * 64];
    const int tid = threadIdx.x, lane = tid & 63, w = tid >> 6;
    const int qi = lane & 15, g = lane >> 4;
    const int bh = blockIdx.x >> 6, qt = blockIdx.x & 63;
    const unsigned short* Qh = Qb + bh * 4096 * 64;
    const unsigned short* Kh = Kb + bh * 4096 * 64;
    const unsigned short* Vh = Vtb + bh * 4096 * 64;  // [64][4096]
    const int trow = qt * 64 + w * 16 + qi;
    const int srow = lane >> 3, sch = (lane & 7) ^ srow;
    const int swz = (qi & 7) << 4;

    bf16x8 qf[2];
    qf[0] = *(const bf16x8*)(Qh + trow * 64 + g * 8);
    qf[1] = *(const bf16x8*)(Qh + trow * 64 + 32 + g * 8);

    f32x4 zero = {0.f, 0.f, 0.f, 0.f};
    f32x4 o[4];
#pragma unroll
    for (int i = 0; i < 4; ++i) o[i] = zero;
    float mi = -__builtin_inff(), li = 0.f;

    for (int j = 0; j <= qt; ++j) {
#pragma unroll
        for (int i = 0; i < 2; ++i) {
            int c = w * 2 + i;
            int row = c * 8 + srow;
            glds16(Kh + (j * 64 + row) * 64 + sch * 8, (char*)lK + c * 1024);
            glds16(Vh + row * 4096 + j * 64 + sch * 8, (char*)lV + c * 1024);
        }
        __syncthreads();

        const bool diag = (j == qt);
        const int kbmax = diag ? (w + 1) : 4;
        f32x4 s[4];
#pragma unroll
        for (int kb = 0; kb < 4; ++kb) s[kb] = zero;
#pragma unroll
        for (int kb = 0; kb < 4; ++kb) {
            if (kb < kbmax) {
                int rk = kb * 16 + qi;
                bf16x8 kf0 = *(const bf16x8*)((const char*)lK + rk * 128 + ((g * 16) ^ swz));
                s[kb] = mfma(kf0, qf[0], s[kb]);
                bf16x8 kf1 = *(const bf16x8*)((const char*)lK + rk * 128 + ((64 + g * 16) ^ swz));
                s[kb] = mfma(kf1, qf[1], s[kb]);
            }
        }
        if (diag) {
#pragma unroll
            for (int kb = 0; kb < 4; ++kb)
#pragma unroll
                for (int r = 0; r < 4; ++r) {
                    int kk = kb * 16 + g * 4 + r;
                    if (kk > w * 16 + qi) s[kb][r] = -__builtin_inff();
                }
        }
        // online softmax (lane-local state: this lane owns q-column qi)
        float mt = s[0][0];
#pragma unroll
        for (int kb = 0; kb < 4; ++kb)
#pragma unroll
            for (int r = 0; r < 4; ++r) mt = fmaxf(mt, s[kb][r]);
        mt = fmaxf(mt, __shfl_xor(mt, 16));
        mt = fmaxf(mt, __shfl_xor(mt, 32));
        float mnew = fmaxf(mi, mt);
        float corr = exp2f(mi - mnew);
        float ls = 0.f;
        unsigned pk[4][2];
#pragma unroll
        for (int kb = 0; kb < 4; ++kb) {
            float p0 = exp2f(s[kb][0] - mnew);
            float p1 = exp2f(s[kb][1] - mnew);
            float p2 = exp2f(s[kb][2] - mnew);
            float p3 = exp2f(s[kb][3] - mnew);
            ls += (p0 + p1) + (p2 + p3);
            pk[kb][0] = (unsigned)f2bf(p0) | ((unsigned)f2bf(p1) << 16);
            pk[kb][1] = (unsigned)f2bf(p2) | ((unsigned)f2bf(p3) << 16);
        }
        ls += __shfl_xor(ls, 16);
        ls += __shfl_xor(ls, 32);
        li = li * corr + ls;
        mi = mnew;
#pragma unroll
        for (int db = 0; db < 4; ++db) o[db] *= corr;

        // PV: rebuild P^T fragment (B-operand: lane needs kk = k2*32+8g+e of its q-column)
        const int k2max = (diag && w < 2) ? 1 : 2;
#pragma unroll
        for (int k2 = 0; k2 < 2; ++k2) {
            if (k2 < k2max) {
                int src0 = qi + (((g & 1) << 1) << 4);  // group 2*(g&1)
                int src1 = src0 + 16;                   // group 2*(g&1)+1
                unsigned a0 = __shfl(pk[2 * k2][0], src0), a1 = __shfl(pk[2 * k2][1], src0);
                unsigned b0 = __shfl(pk[2 * k2 + 1][0], src0), b1 = __shfl(pk[2 * k2 + 1][1], src0);
                unsigned c0 = __shfl(pk[2 * k2][0], src1), c1 = __shfl(pk[2 * k2][1], src1);
                unsigned d0 = __shfl(pk[2 * k2 + 1][0], src1), d1 = __shfl(pk[2 * k2 + 1][1], src1);
                bool hi2 = (g >> 1) != 0;
                union { unsigned u[4]; bf16x8 v; } pf;
                pf.u[0] = hi2 ? b0 : a0;
                pf.u[1] = hi2 ? b1 : a1;
                pf.u[2] = hi2 ? d0 : c0;
                pf.u[3] = hi2 ? d1 : c1;
#pragma unroll
                for (int db = 0; db < 4; ++db) {
                    int rv = db * 16 + qi;
                    bf16x8 vf = *(const bf16x8*)((const char*)lV + rv * 128 + ((k2 * 64 + g * 16) ^ swz));
                    o[db] = mfma(vf, pf.v, o[db]);
                }
            }
        }
        __syncthreads();
    }

    float inv = 1.f / li;
    int b = bh >> 3, h = bh & 7;
    unsigned short* orow = Ob + (b * 4096 + trow) * 512 + h * 64;
#pragma unroll
    for (int db = 0; db < 4; ++db) {
        ushort4 pk4;
        pk4.x = f2bf(o[db][0] * inv);
        pk4.y = f2bf(o[db][1] * inv);
        pk4.z = f2bf(o[db][2] * inv);
        pk4.w = f2bf(o[db][3] * inv);
        *(ushort4*)(orow + db * 16 + g * 4) = pk4;
    }
}

// ---------------- GEMM2: out = Ob[8192x512] @ wprojT[512x512]^T + b (f32 out) ----------------
__global__ __launch_bounds__(256) void k_gemm_proj(
    const unsigned short* __restrict__ Ob, const unsigned short* __restrict__ wT,
    const float* __restrict__ bias, float* __restrict__ out)
{
    __shared__ __attribute__((aligned(16))) unsigned short lA[128 * 64];
    __shared__ __attribute__((aligned(16))) unsigned short lB[128 * 64];
    const int tid = threadIdx.x, lane = tid & 63, w = tid >> 6;
    const int qi = lane & 15, g = lane >> 4;
    const int bm = blockIdx.x & 63, bn = blockIdx.x >> 6;
    const int m0 = bm * 128, n0 = bn * 128;
    const int wr = w >> 1, wc = w & 1;
    const int srow = lane >> 3, sch = (lane & 7) ^ srow;
    const int swz = (qi & 7) << 4;
    f32x4 zero = {0.f, 0.f, 0.f, 0.f};
    f32x4 acc[4][4];
#pragma unroll
    for (int i = 0; i < 4; ++i)
#pragma unroll
        for (int j = 0; j < 4; ++j) acc[i][j] = zero;

    for (int kt = 0; kt < 8; ++kt) {
#pragma unroll
        for (int i = 0; i < 4; ++i) {
            int c = w * 4 + i;
            int row = c * 8 + srow;
            glds16(Ob + (m0 + row) * 512 + kt * 64 + sch * 8, (char*)lA + c * 1024);
            glds16(wT + (n0 + row) * 512 + kt * 64 + sch * 8, (char*)lB + c * 1024);
        }
        __syncthreads();
#pragma unroll
        for (int k2 = 0; k2 < 2; ++k2) {
            bf16x8 af[4], bfr[4];
#pragma unroll
            for (int i = 0; i < 4; ++i) {
                int ra = wr * 64 + i * 16 + qi;
                af[i] = *(const bf16x8*)((const char*)lA + ra * 128 + ((k2 * 64 + g * 16) ^ swz));
                int rb = wc * 64 + i * 16 + qi;
                bfr[i] = *(const bf16x8*)((const char*)lB + rb * 128 + ((k2 * 64 + g * 16) ^ swz));
            }
#pragma unroll
            for (int mi = 0; mi < 4; ++mi)
#pragma unroll
                for (int ni = 0; ni < 4; ++ni)
                    acc[mi][ni] = mfma(af[mi], bfr[ni], acc[mi][ni]);
        }
        __syncthreads();
    }

#pragma unroll
    for (int mi = 0; mi < 4; ++mi) {
        int mbase = m0 + wr * 64 + mi * 16 + g * 4;
#pragma unroll
        for (int ni = 0; ni < 4; ++ni) {
            int n = n0 + wc * 64 + ni * 16 + qi;
            float bn = bias[n];
#pragma unroll
            for (int r = 0; r < 4; ++r)
                out[(mbase + r) * 512 + n] = acc[mi][ni][r] + bn;
        }
    }
}

extern "C" void kernel_launch(void* const* d_in, const int* in_sizes, int n_in,
                              void* d_out, int out_size, void* d_ws, size_t ws_size,
                              hipStream_t stream) {
    const float* x      = (const float*)d_in[0];
    // d_in[1] = mask (causal tril) — implied by kernel structure, unused
    const float* qkv_w  = (const float*)d_in[2];
    const float* qkv_b  = (const float*)d_in[3];
    const float* proj_w = (const float*)d_in[4];
    const float* proj_b = (const float*)d_in[5];

    char* ws = (char*)d_ws;
    unsigned short* xb     = (unsigned short*)(ws);              // 8.0 MB  [8192][512]
    unsigned short* wqkvT  = (unsigned short*)(ws +  8388608);   // 1.5 MB  [1536][512]
    unsigned short* wprojT = (unsigned short*)(ws +  9961472);   // 0.5 MB  [512][512]
    unsigned short* Qb     = (unsigned short*)(ws + 10485760);   // 8.0 MB  [2][8][4096][64]
    unsigned short* Kb     = (unsigned short*)(ws + 18874368);   // 8.0 MB
    unsigned short* Vtb    = (unsigned short*)(ws + 27262976);   // 8.0 MB  [2][8][64][4096]
    unsigned short* Ob     = (unsigned short*)(ws + 35651584);   // 8.0 MB  [8192][512]
    float* out = (float*)d_out;

    k_cast<<<2048, 256, 0, stream>>>(x, xb, 8192 * 512 / 4);
    k_tcast<<<dim3(24, 8), 256, 0, stream>>>(qkv_w, wqkvT, 512, 1536);
    k_tcast<<<dim3(8, 8), 256, 0, stream>>>(proj_w, wprojT, 512, 512);
    k_gemm_qkv<<<768, 256, 0, stream>>>(xb, wqkvT, qkv_b, Qb, Kb, Vtb);
    k_attn<<<1024, 256, 0, stream>>>(Qb, Kb, Vtb, Ob);
    k_gemm_proj<<<256, 256, 0, stream>>>(Ob, wprojT, proj_b, out);
}

// Round 2
// 220.855 us; speedup vs baseline: 1.0351x; 1.0351x over previous
//
#include <hip/hip_runtime.h>
#include <hip/hip_bf16.h>

// MHSA: B=2, T=4096, D=512, H=8, HD=64.
// Needs 42 MB workspace.

typedef __attribute__((ext_vector_type(8))) short bf16x8;
typedef __attribute__((ext_vector_type(4))) float f32x4;

#define DEV static __device__ __forceinline__

DEV unsigned short f2bf(float f) {
    union { float f; unsigned u; } a; a.f = f;
    unsigned r = a.u + 0x7FFFu + ((a.u >> 16) & 1u);   // RNE
    return (unsigned short)(r >> 16);
}

DEV unsigned pack2(float a, float b) {
    __hip_bfloat162 h = __float22bfloat162_rn(make_float2(a, b));
    union { __hip_bfloat162 h; unsigned u; } c; c.h = h; return c.u;
}

DEV void glds16(const void* g, void* l) {
    __builtin_amdgcn_global_load_lds(
        (const __attribute__((address_space(1))) void*)g,
        (__attribute__((address_space(3))) void*)l,
        16, 0, 0);
}

DEV f32x4 mfma(bf16x8 a, bf16x8 b, f32x4 c) {
    return __builtin_amdgcn_mfma_f32_16x16x32_bf16(a, b, c, 0, 0, 0);
}

// ---------------- cast x -> bf16 ----------------
__global__ __launch_bounds__(256) void k_cast(const float* __restrict__ x,
                                              unsigned short* __restrict__ xb, int n4) {
    for (int i = blockIdx.x * 256 + threadIdx.x; i < n4; i += gridDim.x * 256) {
        float4 v = ((const float4*)x)[i];
        ushort4 o;
        o.x = f2bf(v.x); o.y = f2bf(v.y); o.z = f2bf(v.z); o.w = f2bf(v.w);
        ((ushort4*)xb)[i] = o;
    }
}

// ---------------- transpose + cast weight: src f32 [R][C] -> dst bf16 [C][R] ----------------
__global__ __launch_bounds__(256) void k_tcast(const float* __restrict__ src,
                                               unsigned short* __restrict__ dst,
                                               int R, int C) {
    __shared__ float t[64][65];
    const int bx = blockIdx.x, by = blockIdx.y, tid = threadIdx.x;
#pragma unroll
    for (int e = 0; e < 16; ++e) {
        int idx = e * 256 + tid;
        int r = idx >> 6, c = idx & 63;
        t[r][c] = src[(by * 64 + r) * C + bx * 64 + c];
    }
    __syncthreads();
#pragma unroll
    for (int e = 0; e < 16; ++e) {
        int idx = e * 256 + tid;
        int r = idx >> 6, c = idx & 63;
        dst[(bx * 64 + r) * R + by * 64 + c] = f2bf(t[c][r]);
    }
}

// ---------------- GEMM1: qkv = xb[8192x512] @ wT[1536x512]^T + b ----------------
__global__ __launch_bounds__(256) void k_gemm_qkv(
    const unsigned short* __restrict__ xb, const unsigned short* __restrict__ wT,
    const float* __restrict__ bias,
    unsigned short* __restrict__ Qb, unsigned short* __restrict__ Kb,
    unsigned short* __restrict__ Vtb)
{
    __shared__ __attribute__((aligned(16))) unsigned short lA[128 * 64];
    __shared__ __attribute__((aligned(16))) unsigned short lB[128 * 64];
    const int tid = threadIdx.x, lane = tid & 63, w = tid >> 6;
    const int qi = lane & 15, g = lane >> 4;
    const int bm = blockIdx.x & 63, bn = blockIdx.x >> 6;
    const int m0 = bm * 128, n0 = bn * 128;
    const int wr = w >> 1, wc = w & 1;
    const int srow = lane >> 3, sch = (lane & 7) ^ srow;
    const int swz = (qi & 7) << 4;
    f32x4 zero = {0.f, 0.f, 0.f, 0.f};
    f32x4 acc[4][4];
#pragma unroll
    for (int i = 0; i < 4; ++i)
#pragma unroll
        for (int j = 0; j < 4; ++j) acc[i][j] = zero;

    for (int kt = 0; kt < 8; ++kt) {
#pragma unroll
        for (int i = 0; i < 4; ++i) {
            int c = w * 4 + i;
            int row = c * 8 + srow;
            glds16(xb + (m0 + row) * 512 + kt * 64 + sch * 8, (char*)lA + c * 1024);
            glds16(wT + (n0 + row) * 512 + kt * 64 + sch * 8, (char*)lB + c * 1024);
        }
        __syncthreads();
#pragma unroll
        for (int k2 = 0; k2 < 2; ++k2) {
            bf16x8 af[4], bfr[4];
#pragma unroll
            for (int i = 0; i < 4; ++i) {
                int ra = wr * 64 + i * 16 + qi;
                af[i] = *(const bf16x8*)((const char*)lA + ra * 128 + ((k2 * 64 + g * 16) ^ swz));
                int rb = wc * 64 + i * 16 + qi;
                bfr[i] = *(const bf16x8*)((const char*)lB + rb * 128 + ((k2 * 64 + g * 16) ^ swz));
            }
#pragma unroll
            for (int mi = 0; mi < 4; ++mi)
#pragma unroll
                for (int ni = 0; ni < 4; ++ni)
                    acc[mi][ni] = mfma(af[mi], bfr[ni], acc[mi][ni]);
        }
        __syncthreads();
    }

    const int comp = n0 >> 9;  // 0=q 1=k 2=v
#pragma unroll
    for (int mi = 0; mi < 4; ++mi) {
        int mbase = m0 + wr * 64 + mi * 16 + g * 4;
        int b = mbase >> 12, t = mbase & 4095;
#pragma unroll
        for (int ni = 0; ni < 4; ++ni) {
            int n = n0 + wc * 64 + ni * 16 + qi;
            float bn = bias[n];
            int nn = n & 511;
            int h = nn >> 6, d = nn & 63;
            if (comp == 0) {
                unsigned short* dst = Qb + ((b * 8 + h) * 4096 + t) * 64 + d;
#pragma unroll
                for (int r = 0; r < 4; ++r)
                    dst[r * 64] = f2bf((acc[mi][ni][r] + bn) * 0.18033688011112042f);
            } else if (comp == 1) {
                unsigned short* dst = Kb + ((b * 8 + h) * 4096 + t) * 64 + d;
#pragma unroll
                for (int r = 0; r < 4; ++r)
                    dst[r * 64] = f2bf(acc[mi][ni][r] + bn);
            } else {
                ushort4 pk4;
                pk4.x = f2bf(acc[mi][ni][0] + bn);
                pk4.y = f2bf(acc[mi][ni][1] + bn);
                pk4.z = f2bf(acc[mi][ni][2] + bn);
                pk4.w = f2bf(acc[mi][ni][3] + bn);
                *(ushort4*)(Vtb + ((b * 8 + h) * 64 + d) * 4096 + t) = pk4;
            }
        }
    }
}

// ---------------- flash attention (causal) ----------------
// Block = 4 waves, 64 q-rows (16/wave). Each block processes TWO q-tiles
// (qt = 63-p then qt = p) so every block does exactly 33 KV-tile iterations
// of 128 KV rows -> uniform work, no tail. Double-buffered LDS, prefetch
// next KV tile before computing current (one barrier per tile).
__global__ __launch_bounds__(256) void k_attn(
    const unsigned short* __restrict__ Qb, const unsigned short* __restrict__ Kb,
    const unsigned short* __restrict__ Vtb, unsigned short* __restrict__ Ob)
{
    __shared__ __attribute__((aligned(16))) unsigned short lK[2][128 * 64];
    __shared__ __attribute__((aligned(16))) unsigned short lV[2][64 * 128];
    const int tid = threadIdx.x, lane = tid & 63, w = tid >> 6;
    const int qi = lane & 15, g = lane >> 4;
    const int idx = blockIdx.x;
    // XCD-aware: XCD x (= idx%8) sees only heads {2x, 2x+1} -> 2MB K/V per L2
    const int bh = ((idx & 7) << 1) | (idx >> 8);
    const int p = (idx >> 3) & 31;
    const unsigned short* Qh = Qb + bh * 4096 * 64;
    const unsigned short* Kh = Kb + bh * 4096 * 64;
    const unsigned short* Vh = Vtb + bh * 4096 * 64;  // [64][4096]
    const int b = bh >> 3, h = bh & 7;
    const int swz = (qi & 7) << 4;
    const int srowK = lane >> 3, schK = (lane & 7) ^ srowK;
    const int srowV = lane >> 4;                      // 0..3
    const float NEGINF = -__builtin_inff();
    f32x4 zero = {0.f, 0.f, 0.f, 0.f};

    for (int si = 0; si < 2; ++si) {
        const int qt = si ? p : 63 - p;
        const int nt = (qt + 2) >> 1;                 // KV tiles of 128 rows
        const int trow = qt * 64 + w * 16 + qi;
        bf16x8 qf0 = *(const bf16x8*)(Qh + trow * 64 + g * 8);
        bf16x8 qf1 = *(const bf16x8*)(Qh + trow * 64 + 32 + g * 8);
        f32x4 o[4];
#pragma unroll
        for (int i = 0; i < 4; ++i) o[i] = zero;
        float mi = NEGINF, li = 0.f;

        // stage tile 0 into buf 0
#pragma unroll
        for (int i = 0; i < 4; ++i) {
            int c = w * 4 + i;
            int rowk = c * 8 + srowK;
            glds16(Kh + rowk * 64 + schK * 8, (char*)lK[0] + c * 1024);
            int rowv = c * 4 + srowV;
            int chv = (lane & 15) ^ (rowv & 7);
            glds16(Vh + rowv * 4096 + chv * 8, (char*)lV[0] + c * 1024);
        }
        __syncthreads();

        for (int j = 0; j < nt; ++j) {
            const int cur = j & 1;
            if (j + 1 < nt) {
#pragma unroll
                for (int i = 0; i < 4; ++i) {
                    int c = w * 4 + i;
                    int rowk = c * 8 + srowK;
                    glds16(Kh + ((j + 1) * 128 + rowk) * 64 + schK * 8,
                           (char*)lK[cur ^ 1] + c * 1024);
                    int rowv = c * 4 + srowV;
                    int chv = (lane & 15) ^ (rowv & 7);
                    glds16(Vh + rowv * 4096 + (j + 1) * 128 + chv * 8,
                           (char*)lV[cur ^ 1] + c * 1024);
                }
            }

            const bool last = (j == nt - 1);
            const int relw = qt * 64 + w * 16 + 15 - j * 128;   // >= 15 on last tile
            const int kbmax = last ? (((relw >> 4) + 1) > 8 ? 8 : ((relw >> 4) + 1)) : 8;
            const int k2max = last ? (((relw >> 5) + 1) > 4 ? 4 : ((relw >> 5) + 1)) : 4;

            f32x4 s[8];
#pragma unroll
            for (int kb = 0; kb < 8; ++kb) s[kb] = zero;
            __builtin_amdgcn_s_setprio(1);
#pragma unroll
            for (int kb = 0; kb < 8; ++kb) {
                if (kb < kbmax) {
                    int rk = kb * 16 + qi;
                    bf16x8 kf0 = *(const bf16x8*)((const char*)lK[cur] + rk * 128 + ((g * 16) ^ swz));
                    s[kb] = mfma(kf0, qf0, s[kb]);
                    bf16x8 kf1 = *(const bf16x8*)((const char*)lK[cur] + rk * 128 + ((64 + g * 16) ^ swz));
                    s[kb] = mfma(kf1, qf1, s[kb]);
                }
            }
            __builtin_amdgcn_s_setprio(0);

            if (last) {
                int qrel = trow - j * 128;
#pragma unroll
                for (int kb = 0; kb < 8; ++kb)
#pragma unroll
                    for (int r = 0; r < 4; ++r) {
                        int kk = kb * 16 + g * 4 + r;
                        if (kk > qrel) s[kb][r] = NEGINF;
                    }
            }

            // online softmax: lane owns q-column qi; rows split across groups g
            float mt = s[0][0];
#pragma unroll
            for (int kb = 0; kb < 8; ++kb)
#pragma unroll
                for (int r = 0; r < 4; ++r) mt = fmaxf(mt, s[kb][r]);
            mt = fmaxf(mt, __shfl_xor(mt, 16));
            mt = fmaxf(mt, __shfl_xor(mt, 32));
            // defer-max (T13): rescale only if max grew by > 8 (log2 units)
            if (!__all(mt - mi <= 8.0f)) {
                float mnew = fmaxf(mi, mt);
                float corr = exp2f(mi - mnew);
                li *= corr;
#pragma unroll
                for (int db = 0; db < 4; ++db) o[db] *= corr;
                mi = mnew;
            }
            float ls = 0.f;
            unsigned pk[8][2];
#pragma unroll
            for (int kb = 0; kb < 8; ++kb) {
                float p0 = exp2f(s[kb][0] - mi);
                float p1 = exp2f(s[kb][1] - mi);
                float p2 = exp2f(s[kb][2] - mi);
                float p3 = exp2f(s[kb][3] - mi);
                ls += (p0 + p1) + (p2 + p3);
                pk[kb][0] = pack2(p0, p1);
                pk[kb][1] = pack2(p2, p3);
            }
            ls += __shfl_xor(ls, 16);
            ls += __shfl_xor(ls, 32);
            li += ls;

            // PV: rebuild P^T B-fragments via shuffles, A = V^T from LDS
#pragma unroll
            for (int k2 = 0; k2 < 4; ++k2) {
                if (k2 < k2max) {
                    int src0 = qi + (((g & 1) << 1) << 4);
                    int src1 = src0 + 16;
                    unsigned a0 = __shfl(pk[2 * k2][0], src0), a1 = __shfl(pk[2 * k2][1], src0);
                    unsigned b0 = __shfl(pk[2 * k2 + 1][0], src0), b1 = __shfl(pk[2 * k2 + 1][1], src0);
                    unsigned c0 = __shfl(pk[2 * k2][0], src1), c1 = __shfl(pk[2 * k2][1], src1);
                    unsigned d0 = __shfl(pk[2 * k2 + 1][0], src1), d1 = __shfl(pk[2 * k2 + 1][1], src1);
                    bool hi2 = (g >> 1) != 0;
                    union { unsigned u[4]; bf16x8 v; } pf;
                    pf.u[0] = hi2 ? b0 : a0;
                    pf.u[1] = hi2 ? b1 : a1;
                    pf.u[2] = hi2 ? d0 : c0;
                    pf.u[3] = hi2 ? d1 : c1;
                    __builtin_amdgcn_s_setprio(1);
#pragma unroll
                    for (int db = 0; db < 4; ++db) {
                        int rv = db * 16 + qi;
                        bf16x8 vf = *(const bf16x8*)((const char*)lV[cur] + rv * 256 + ((k2 * 64 + g * 16) ^ swz));
                        o[db] = mfma(vf, pf.v, o[db]);
                    }
                    __builtin_amdgcn_s_setprio(0);
                }
            }
            __syncthreads();
        }

        float inv = 1.f / li;
        unsigned short* orow = Ob + (b * 4096 + trow) * 512 + h * 64;
#pragma unroll
        for (int db = 0; db < 4; ++db) {
            union { ushort4 s4; uint2 u2; } ov;
            ov.u2.x = pack2(o[db][0] * inv, o[db][1] * inv);
            ov.u2.y = pack2(o[db][2] * inv, o[db][3] * inv);
            *(ushort4*)(orow + db * 16 + g * 4) = ov.s4;
        }
    }
}

// ---------------- GEMM2: out = Ob[8192x512] @ wprojT[512x512]^T + b (f32 out) ----------------
__global__ __launch_bounds__(256) void k_gemm_proj(
    const unsigned short* __restrict__ Ob, const unsigned short* __restrict__ wT,
    const float* __restrict__ bias, float* __restrict__ out)
{
    __shared__ __attribute__((aligned(16))) unsigned short lA[128 * 64];
    __shared__ __attribute__((aligned(16))) unsigned short lB[128 * 64];
    const int tid = threadIdx.x, lane = tid & 63, w = tid >> 6;
    const int qi = lane & 15, g = lane >> 4;
    const int bm = blockIdx.x & 63, bn = blockIdx.x >> 6;
    const int m0 = bm * 128, n0 = bn * 128;
    const int wr = w >> 1, wc = w & 1;
    const int srow = lane >> 3, sch = (lane & 7) ^ srow;
    const int swz = (qi & 7) << 4;
    f32x4 zero = {0.f, 0.f, 0.f, 0.f};
    f32x4 acc[4][4];
#pragma unroll
    for (int i = 0; i < 4; ++i)
#pragma unroll
        for (int j = 0; j < 4; ++j) acc[i][j] = zero;

    for (int kt = 0; kt < 8; ++kt) {
#pragma unroll
        for (int i = 0; i < 4; ++i) {
            int c = w * 4 + i;
            int row = c * 8 + srow;
            glds16(Ob + (m0 + row) * 512 + kt * 64 + sch * 8, (char*)lA + c * 1024);
            glds16(wT + (n0 + row) * 512 + kt * 64 + sch * 8, (char*)lB + c * 1024);
        }
        __syncthreads();
#pragma unroll
        for (int k2 = 0; k2 < 2; ++k2) {
            bf16x8 af[4], bfr[4];
#pragma unroll
            for (int i = 0; i < 4; ++i) {
                int ra = wr * 64 + i * 16 + qi;
                af[i] = *(const bf16x8*)((const char*)lA + ra * 128 + ((k2 * 64 + g * 16) ^ swz));
                int rb = wc * 64 + i * 16 + qi;
                bfr[i] = *(const bf16x8*)((const char*)lB + rb * 128 + ((k2 * 64 + g * 16) ^ swz));
            }
#pragma unroll
            for (int mi = 0; mi < 4; ++mi)
#pragma unroll
                for (int ni = 0; ni < 4; ++ni)
                    acc[mi][ni] = mfma(af[mi], bfr[ni], acc[mi][ni]);
        }
        __syncthreads();
    }

#pragma unroll
    for (int mi = 0; mi < 4; ++mi) {
        int mbase = m0 + wr * 64 + mi * 16 + g * 4;
#pragma unroll
        for (int ni = 0; ni < 4; ++ni) {
            int n = n0 + wc * 64 + ni * 16 + qi;
            float bn = bias[n];
#pragma unroll
            for (int r = 0; r < 4; ++r)
                out[(mbase + r) * 512 + n] = acc[mi][ni][r] + bn;
        }
    }
}

extern "C" void kernel_launch(void* const* d_in, const int* in_sizes, int n_in,
                              void* d_out, int out_size, void* d_ws, size_t ws_size,
                              hipStream_t stream) {
    const float* x      = (const float*)d_in[0];
    const float* qkv_w  = (const float*)d_in[2];
    const float* qkv_b  = (const float*)d_in[3];
    const float* proj_w = (const float*)d_in[4];
    const float* proj_b = (const float*)d_in[5];

    char* ws = (char*)d_ws;
    unsigned short* xb     = (unsigned short*)(ws);              // 8.0 MB  [8192][512]
    unsigned short* wqkvT  = (unsigned short*)(ws +  8388608);   // 1.5 MB  [1536][512]
    unsigned short* wprojT = (unsigned short*)(ws +  9961472);   // 0.5 MB  [512][512]
    unsigned short* Qb     = (unsigned short*)(ws + 10485760);   // 8.0 MB  [2][8][4096][64]
    unsigned short* Kb     = (unsigned short*)(ws + 18874368);   // 8.0 MB
    unsigned short* Vtb    = (unsigned short*)(ws + 27262976);   // 8.0 MB  [2][8][64][4096]
    unsigned short* Ob     = (unsigned short*)(ws + 35651584);   // 8.0 MB  [8192][512]
    float* out = (float*)d_out;

    k_cast<<<2048, 256, 0, stream>>>(x, xb, 8192 * 512 / 4);
    k_tcast<<<dim3(24, 8), 256, 0, stream>>>(qkv_w, wqkvT, 512, 1536);
    k_tcast<<<dim3(8, 8), 256, 0, stream>>>(proj_w, wprojT, 512, 512);
    k_gemm_qkv<<<768, 256, 0, stream>>>(xb, wqkvT, qkv_b, Qb, Kb, Vtb);
    k_attn<<<512, 256, 0, stream>>>(Qb, Kb, Vtb, Ob);
    k_gemm_proj<<<256, 256, 0, stream>>>(Ob, wprojT, proj_b, out);
}

// Round 4
// 159.802 us; speedup vs baseline: 1.4306x; 1.3821x over previous
//
#include <hip/hip_runtime.h>
#include <hip/hip_bf16.h>

// MHSA: B=2, T=4096, D=512, H=8, HD=64.
// Needs 42 MB workspace.

typedef __attribute__((ext_vector_type(8))) short bf16x8;
typedef __attribute__((ext_vector_type(4))) float f32x4;
typedef __attribute__((ext_vector_type(16))) float f32x16;
typedef __attribute__((ext_vector_type(2))) int i32x2;

#define DEV static __device__ __forceinline__

DEV unsigned short f2bf(float f) {
    union { float f; unsigned u; } a; a.f = f;
    unsigned r = a.u + 0x7FFFu + ((a.u >> 16) & 1u);   // RNE
    return (unsigned short)(r >> 16);
}

DEV unsigned pack2(float a, float b) {
    __hip_bfloat162 h = __float22bfloat162_rn(make_float2(a, b));
    union { __hip_bfloat162 h; unsigned u; } c; c.h = h; return c.u;
}

DEV void glds16(const void* g, void* l) {
    __builtin_amdgcn_global_load_lds(
        (const __attribute__((address_space(1))) void*)g,
        (__attribute__((address_space(3))) void*)l,
        16, 0, 0);
}

DEV f32x4 mfma(bf16x8 a, bf16x8 b, f32x4 c) {
    return __builtin_amdgcn_mfma_f32_16x16x32_bf16(a, b, c, 0, 0, 0);
}

DEV f32x16 mfma32(bf16x8 a, bf16x8 b, f32x16 c) {
    return __builtin_amdgcn_mfma_f32_32x32x16_bf16(a, b, c, 0, 0, 0);
}

// v_permlane32_swap_b32 (S1 semantics): upper 32 lanes of first operand are
// swapped with lower 32 lanes of second operand:
//   new_a[32+i] = old_b[i]; new_b[i] = old_a[32+i]; other lanes unchanged.
// Call as plswap(lowWord, highWord) -> (a,b) become (pf_low, pf_high).
DEV void plswap(unsigned& a, unsigned& b) {
#if __has_builtin(__builtin_amdgcn_permlane32_swap)
    i32x2 r = __builtin_amdgcn_permlane32_swap((int)a, (int)b, false, false);
    a = (unsigned)r.x; b = (unsigned)r.y;
#else
    unsigned sa = __shfl_xor(a, 32), sb = __shfl_xor(b, 32);
    bool hi = (threadIdx.x & 32) != 0;
    unsigned na = hi ? sb : a;   // lanes>=32 take b's lower half
    unsigned nb = hi ? b : sa;   // lanes<32 take a's upper half
    a = na; b = nb;
#endif
}

// ---------------- cast x -> bf16 ----------------
__global__ __launch_bounds__(256) void k_cast(const float* __restrict__ x,
                                              unsigned short* __restrict__ xb, int n4) {
    for (int i = blockIdx.x * 256 + threadIdx.x; i < n4; i += gridDim.x * 256) {
        float4 v = ((const float4*)x)[i];
        ushort4 o;
        o.x = f2bf(v.x); o.y = f2bf(v.y); o.z = f2bf(v.z); o.w = f2bf(v.w);
        ((ushort4*)xb)[i] = o;
    }
}

// ---------------- transpose + cast weight: src f32 [R][C] -> dst bf16 [C][R] ----------------
__global__ __launch_bounds__(256) void k_tcast(const float* __restrict__ src,
                                               unsigned short* __restrict__ dst,
                                               int R, int C) {
    __shared__ float t[64][65];
    const int bx = blockIdx.x, by = blockIdx.y, tid = threadIdx.x;
#pragma unroll
    for (int e = 0; e < 16; ++e) {
        int idx = e * 256 + tid;
        int r = idx >> 6, c = idx & 63;
        t[r][c] = src[(by * 64 + r) * C + bx * 64 + c];
    }
    __syncthreads();
#pragma unroll
    for (int e = 0; e < 16; ++e) {
        int idx = e * 256 + tid;
        int r = idx >> 6, c = idx & 63;
        dst[(bx * 64 + r) * R + by * 64 + c] = f2bf(t[c][r]);
    }
}

// ---------------- GEMM1: qkv = xb[8192x512] @ wT[1536x512]^T + b ----------------
__global__ __launch_bounds__(256) void k_gemm_qkv(
    const unsigned short* __restrict__ xb, const unsigned short* __restrict__ wT,
    const float* __restrict__ bias,
    unsigned short* __restrict__ Qb, unsigned short* __restrict__ Kb,
    unsigned short* __restrict__ Vtb)
{
    __shared__ __attribute__((aligned(16))) unsigned short lA[128 * 64];
    __shared__ __attribute__((aligned(16))) unsigned short lB[128 * 64];
    const int tid = threadIdx.x, lane = tid & 63, w = tid >> 6;
    const int qi = lane & 15, g = lane >> 4;
    const int bm = blockIdx.x & 63, bn = blockIdx.x >> 6;
    const int m0 = bm * 128, n0 = bn * 128;
    const int wr = w >> 1, wc = w & 1;
    const int srow = lane >> 3, sch = (lane & 7) ^ srow;
    const int swz = (qi & 7) << 4;
    f32x4 zero = {0.f, 0.f, 0.f, 0.f};
    f32x4 acc[4][4];
#pragma unroll
    for (int i = 0; i < 4; ++i)
#pragma unroll
        for (int j = 0; j < 4; ++j) acc[i][j] = zero;

    for (int kt = 0; kt < 8; ++kt) {
#pragma unroll
        for (int i = 0; i < 4; ++i) {
            int c = w * 4 + i;
            int row = c * 8 + srow;
            glds16(xb + (m0 + row) * 512 + kt * 64 + sch * 8, (char*)lA + c * 1024);
            glds16(wT + (n0 + row) * 512 + kt * 64 + sch * 8, (char*)lB + c * 1024);
        }
        __syncthreads();
#pragma unroll
        for (int k2 = 0; k2 < 2; ++k2) {
            bf16x8 af[4], bfr[4];
#pragma unroll
            for (int i = 0; i < 4; ++i) {
                int ra = wr * 64 + i * 16 + qi;
                af[i] = *(const bf16x8*)((const char*)lA + ra * 128 + ((k2 * 64 + g * 16) ^ swz));
                int rb = wc * 64 + i * 16 + qi;
                bfr[i] = *(const bf16x8*)((const char*)lB + rb * 128 + ((k2 * 64 + g * 16) ^ swz));
            }
#pragma unroll
            for (int mi = 0; mi < 4; ++mi)
#pragma unroll
                for (int ni = 0; ni < 4; ++ni)
                    acc[mi][ni] = mfma(af[mi], bfr[ni], acc[mi][ni]);
        }
        __syncthreads();
    }

    const int comp = n0 >> 9;  // 0=q 1=k 2=v
#pragma unroll
    for (int mi = 0; mi < 4; ++mi) {
        int mbase = m0 + wr * 64 + mi * 16 + g * 4;
        int b = mbase >> 12, t = mbase & 4095;
#pragma unroll
        for (int ni = 0; ni < 4; ++ni) {
            int n = n0 + wc * 64 + ni * 16 + qi;
            float bn = bias[n];
            int nn = n & 511;
            int h = nn >> 6, d = nn & 63;
            if (comp == 0) {
                unsigned short* dst = Qb + ((b * 8 + h) * 4096 + t) * 64 + d;
#pragma unroll
                for (int r = 0; r < 4; ++r)
                    dst[r * 64] = f2bf((acc[mi][ni][r] + bn) * 0.18033688011112042f);
            } else if (comp == 1) {
                unsigned short* dst = Kb + ((b * 8 + h) * 4096 + t) * 64 + d;
#pragma unroll
                for (int r = 0; r < 4; ++r)
                    dst[r * 64] = f2bf(acc[mi][ni][r] + bn);
            } else {
                ushort4 pk4;
                pk4.x = f2bf(acc[mi][ni][0] + bn);
                pk4.y = f2bf(acc[mi][ni][1] + bn);
                pk4.z = f2bf(acc[mi][ni][2] + bn);
                pk4.w = f2bf(acc[mi][ni][3] + bn);
                *(ushort4*)(Vtb + ((b * 8 + h) * 64 + d) * 4096 + t) = pk4;
            }
        }
    }
}

// ---------------- flash attention (causal), 32x32 MFMA structure ----------------
// Block = 4 waves x 32 q-rows = 128 q-rows. KV tiles of 64, double-buffered LDS,
// XOR-swizzled K [64k][64d] and Vt [64d][64k]. Swapped QK^T (lane owns q-col),
// P^T fragments via cvt_pk + permlane32_swap, O^T accumulation (lane-q-local
// softmax state). Grid 512, LPT order (big q-blocks first).
__global__ __launch_bounds__(256) void k_attn(
    const unsigned short* __restrict__ Qb, const unsigned short* __restrict__ Kb,
    const unsigned short* __restrict__ Vtb, unsigned short* __restrict__ Ob)
{
    __shared__ __attribute__((aligned(16))) unsigned short lKb[2][4096];
    __shared__ __attribute__((aligned(16))) unsigned short lVb[2][4096];
    const int tid = threadIdx.x, lane = tid & 63, w = tid >> 6;
    const int l31 = lane & 31, l7 = lane & 7, h = lane >> 5;
    const int idx = blockIdx.x;
    const int bh = idx & 15;
    const int qb = 31 - (idx >> 4);            // LPT: longest q-blocks first
    const unsigned short* Qh = Qb + bh * 4096 * 64;
    const unsigned short* Kh = Kb + bh * 4096 * 64;
    const unsigned short* Vh = Vtb + bh * 4096 * 64;   // [64 d][4096 k]
    const float NEGINF = -__builtin_inff();

    const int qrow = qb * 128 + w * 32 + l31;
    const int jdiag = 2 * qb + (w >> 1);
    const int nt = 2 * qb + 2;

    // staging offsets (global, elements); LDS dest = uniform base + lane*16B
    const int srw = lane >> 3;                 // 0..7
    const int sxor = (l7 ^ srw) * 8;
    const int kOff = (w * 16 + srw) * 64 + sxor;       // + j*4096 + i*512
    const int vOff = (w * 16 + srw) * 4096 + sxor;     // + i*32768 + j*64
    const int ldsOff = w * 2048;                        // + i*1024 (bytes)

    // fragment read offsets
    const int rowbase = l31 * 128;             // bytes
    int cx[4];
#pragma unroll
    for (int c = 0; c < 4; ++c) cx[c] = ((2 * c + h) ^ l7) * 16;

    // Q fragments (B-operand): lane holds q-col l31, d = 16c + 8h + e
    bf16x8 qf[4];
#pragma unroll
    for (int c = 0; c < 4; ++c)
        qf[c] = *(const bf16x8*)(Qh + qrow * 64 + 16 * c + 8 * h);

    f32x16 o0, o1;
#pragma unroll
    for (int r = 0; r < 16; ++r) { o0[r] = 0.f; o1[r] = 0.f; }
    float mi = NEGINF, li = 0.f;

    // stage tile 0 -> buf 0
#pragma unroll
    for (int i = 0; i < 2; ++i) {
        glds16(Kh + kOff + i * 512, (char*)lKb[0] + ldsOff + i * 1024);
        glds16(Vh + vOff + i * 32768, (char*)lVb[0] + ldsOff + i * 1024);
    }
    __syncthreads();

    for (int j = 0; j < nt; ++j) {
        const int cur = j & 1;
        if (j + 1 < nt) {
#pragma unroll
            for (int i = 0; i < 2; ++i) {
                glds16(Kh + (j + 1) * 4096 + kOff + i * 512,
                       (char*)lKb[cur ^ 1] + ldsOff + i * 1024);
                glds16(Vh + vOff + i * 32768 + (j + 1) * 64,
                       (char*)lVb[cur ^ 1] + ldsOff + i * 1024);
            }
        }

        if (j <= jdiag) {
            const char* lk = (const char*)lKb[cur];
            const char* lv = (const char*)lVb[cur];
            // ---- QK^T: S^T[k][q], lane = q-col, regs = 16 k-rows per subtile
            f32x16 s0, s1;
#pragma unroll
            for (int r = 0; r < 16; ++r) { s0[r] = 0.f; s1[r] = 0.f; }
            __builtin_amdgcn_s_setprio(1);
#pragma unroll
            for (int c = 0; c < 4; ++c) {
                bf16x8 k0 = *(const bf16x8*)(lk + rowbase + cx[c]);
                bf16x8 k1 = *(const bf16x8*)(lk + 4096 + rowbase + cx[c]);
                s0 = mfma32(k0, qf[c], s0);
                s1 = mfma32(k1, qf[c], s1);
            }
            __builtin_amdgcn_s_setprio(0);

            // ---- causal mask on diagonal tile
            if (j == jdiag) {
                const int kb0 = j * 64 + 4 * h;
#pragma unroll
                for (int r = 0; r < 16; ++r) {
                    int ka = kb0 + (r & 3) + 8 * (r >> 2);
                    if (ka > qrow) s0[r] = NEGINF;
                    if (ka + 32 > qrow) s1[r] = NEGINF;
                }
            }

            // ---- online softmax (lane-local state for q-col l31)
            float mt = s0[0];
#pragma unroll
            for (int r = 0; r < 16; ++r) { mt = fmaxf(mt, s0[r]); mt = fmaxf(mt, s1[r]); }
            mt = fmaxf(mt, __shfl_xor(mt, 32));
            if (!__all(mt - mi <= 8.0f)) {          // defer-max (T13)
                float mnew = fmaxf(mi, mt);
                float corr = __builtin_amdgcn_exp2f(mi - mnew);
                li *= corr;
#pragma unroll
                for (int r = 0; r < 16; ++r) { o0[r] *= corr; o1[r] *= corr; }
                mi = mnew;
            }
            float ls = 0.f;
#pragma unroll
            for (int r = 0; r < 16; ++r) {
                s0[r] = __builtin_amdgcn_exp2f(s0[r] - mi); ls += s0[r];
                s1[r] = __builtin_amdgcn_exp2f(s1[r] - mi); ls += s1[r];
            }
            ls += __shfl_xor(ls, 32);
            li += ls;

            // ---- PV: O^T += V^T-frag x P-frag, per 16-k chunk
            __builtin_amdgcn_s_setprio(1);
#pragma unroll
            for (int c2 = 0; c2 < 4; ++c2) {
                unsigned u0, u1, u2, u3;
                if (c2 < 2) {
                    const int b0 = 8 * c2;
                    u0 = pack2(s0[b0 + 0], s0[b0 + 1]);
                    u1 = pack2(s0[b0 + 2], s0[b0 + 3]);
                    u2 = pack2(s0[b0 + 4], s0[b0 + 5]);
                    u3 = pack2(s0[b0 + 6], s0[b0 + 7]);
                } else {
                    const int b0 = 8 * (c2 - 2);
                    u0 = pack2(s1[b0 + 0], s1[b0 + 1]);
                    u1 = pack2(s1[b0 + 2], s1[b0 + 3]);
                    u2 = pack2(s1[b0 + 4], s1[b0 + 5]);
                    u3 = pack2(s1[b0 + 6], s1[b0 + 7]);
                }
                // (low, high) word pairs: own-k words in, B-fragment words out
                plswap(u0, u2);    // -> pf.u[0], pf.u[2]
                plswap(u1, u3);    // -> pf.u[1], pf.u[3]
                union { unsigned u[4]; bf16x8 v; } pf;
                pf.u[0] = u0; pf.u[1] = u1; pf.u[2] = u2; pf.u[3] = u3;
                bf16x8 v0 = *(const bf16x8*)(lv + rowbase + cx[c2]);
                bf16x8 v1 = *(const bf16x8*)(lv + 4096 + rowbase + cx[c2]);
                o0 = mfma32(v0, pf.v, o0);
                o1 = mfma32(v1, pf.v, o1);
            }
            __builtin_amdgcn_s_setprio(0);
        }
        __syncthreads();
    }

    // ---- epilogue: lane owns q-col qrow; regs = d rows
    float inv = 1.f / li;
    unsigned short* orow = Ob + ((bh >> 3) * 4096 + qrow) * 512 + (bh & 7) * 64 + 4 * h;
#pragma unroll
    for (int g2 = 0; g2 < 4; ++g2) {
        union { ushort4 s4; unsigned u[2]; } a;
        a.u[0] = pack2(o0[4 * g2 + 0] * inv, o0[4 * g2 + 1] * inv);
        a.u[1] = pack2(o0[4 * g2 + 2] * inv, o0[4 * g2 + 3] * inv);
        *(ushort4*)(orow + 8 * g2) = a.s4;
        a.u[0] = pack2(o1[4 * g2 + 0] * inv, o1[4 * g2 + 1] * inv);
        a.u[1] = pack2(o1[4 * g2 + 2] * inv, o1[4 * g2 + 3] * inv);
        *(ushort4*)(orow + 32 + 8 * g2) = a.s4;
    }
}

// ---------------- GEMM2: out = Ob[8192x512] @ wprojT[512x512]^T + b (f32 out) ----------------
__global__ __launch_bounds__(256) void k_gemm_proj(
    const unsigned short* __restrict__ Ob, const unsigned short* __restrict__ wT,
    const float* __restrict__ bias, float* __restrict__ out)
{
    __shared__ __attribute__((aligned(16))) unsigned short lA[128 * 64];
    __shared__ __attribute__((aligned(16))) unsigned short lB[128 * 64];
    const int tid = threadIdx.x, lane = tid & 63, w = tid >> 6;
    const int qi = lane & 15, g = lane >> 4;
    const int bm = blockIdx.x & 63, bn = blockIdx.x >> 6;
    const int m0 = bm * 128, n0 = bn * 128;
    const int wr = w >> 1, wc = w & 1;
    const int srow = lane >> 3, sch = (lane & 7) ^ srow;
    const int swz = (qi & 7) << 4;
    f32x4 zero = {0.f, 0.f, 0.f, 0.f};
    f32x4 acc[4][4];
#pragma unroll
    for (int i = 0; i < 4; ++i)
#pragma unroll
        for (int j = 0; j < 4; ++j) acc[i][j] = zero;

    for (int kt = 0; kt < 8; ++kt) {
#pragma unroll
        for (int i = 0; i < 4; ++i) {
            int c = w * 4 + i;
            int row = c * 8 + srow;
            glds16(Ob + (m0 + row) * 512 + kt * 64 + sch * 8, (char*)lA + c * 1024);
            glds16(wT + (n0 + row) * 512 + kt * 64 + sch * 8, (char*)lB + c * 1024);
        }
        __syncthreads();
#pragma unroll
        for (int k2 = 0; k2 < 2; ++k2) {
            bf16x8 af[4], bfr[4];
#pragma unroll
            for (int i = 0; i < 4; ++i) {
                int ra = wr * 64 + i * 16 + qi;
                af[i] = *(const bf16x8*)((const char*)lA + ra * 128 + ((k2 * 64 + g * 16) ^ swz));
                int rb = wc * 64 + i * 16 + qi;
                bfr[i] = *(const bf16x8*)((const char*)lB + rb * 128 + ((k2 * 64 + g * 16) ^ swz));
            }
#pragma unroll
            for (int mi = 0; mi < 4; ++mi)
#pragma unroll
                for (int ni = 0; ni < 4; ++ni)
                    acc[mi][ni] = mfma(af[mi], bfr[ni], acc[mi][ni]);
        }
        __syncthreads();
    }

#pragma unroll
    for (int mi = 0; mi < 4; ++mi) {
        int mbase = m0 + wr * 64 + mi * 16 + g * 4;
#pragma unroll
        for (int ni = 0; ni < 4; ++ni) {
            int n = n0 + wc * 64 + ni * 16 + qi;
            float bn = bias[n];
#pragma unroll
            for (int r = 0; r < 4; ++r)
                out[(mbase + r) * 512 + n] = acc[mi][ni][r] + bn;
        }
    }
}

extern "C" void kernel_launch(void* const* d_in, const int* in_sizes, int n_in,
                              void* d_out, int out_size, void* d_ws, size_t ws_size,
                              hipStream_t stream) {
    const float* x      = (const float*)d_in[0];
    const float* qkv_w  = (const float*)d_in[2];
    const float* qkv_b  = (const float*)d_in[3];
    const float* proj_w = (const float*)d_in[4];
    const float* proj_b = (const float*)d_in[5];

    char* ws = (char*)d_ws;
    unsigned short* xb     = (unsigned short*)(ws);              // 8.0 MB  [8192][512]
    unsigned short* wqkvT  = (unsigned short*)(ws +  8388608);   // 1.5 MB  [1536][512]
    unsigned short* wprojT = (unsigned short*)(ws +  9961472);   // 0.5 MB  [512][512]
    unsigned short* Qb     = (unsigned short*)(ws + 10485760);   // 8.0 MB  [2][8][4096][64]
    unsigned short* Kb     = (unsigned short*)(ws + 18874368);   // 8.0 MB
    unsigned short* Vtb    = (unsigned short*)(ws + 27262976);   // 8.0 MB  [2][8][64][4096]
    unsigned short* Ob     = (unsigned short*)(ws + 35651584);   // 8.0 MB  [8192][512]
    float* out = (float*)d_out;

    k_cast<<<2048, 256, 0, stream>>>(x, xb, 8192 * 512 / 4);
    k_tcast<<<dim3(24, 8), 256, 0, stream>>>(qkv_w, wqkvT, 512, 1536);
    k_tcast<<<dim3(8, 8), 256, 0, stream>>>(proj_w, wprojT, 512, 512);
    k_gemm_qkv<<<768, 256, 0, stream>>>(xb, wqkvT, qkv_b, Qb, Kb, Vtb);
    k_attn<<<512, 256, 0, stream>>>(Qb, Kb, Vtb, Ob);
    k_gemm_proj<<<256, 256, 0, stream>>>(Ob, wprojT, proj_b, out);
}